// Round 1
// baseline (136.540 us; speedup 1.0000x reference)
//
#include <hip/hip_runtime.h>
#include <math.h>

#define HDIM 128

// ---------------------------------------------------------------------------
// init: starts[s] = T for all s in [0, B]; zero the scalar output.
// ---------------------------------------------------------------------------
__global__ void init_kernel(int* __restrict__ starts, int nB1, int Tval,
                            float* __restrict__ out) {
    int i = blockIdx.x * blockDim.x + threadIdx.x;
    if (i < nB1) starts[i] = Tval;
    if (i == 0) out[0] = 0.0f;
}

// ---------------------------------------------------------------------------
// segment_ids is sorted: starts[s] = first t with seg[t] >= s.
// Boundary thread t (seg[t-1] != seg[t]) fills starts for the covered range;
// trailing empty segments keep the init value T.
// ---------------------------------------------------------------------------
__global__ void seg_bounds_kernel(const int* __restrict__ seg,
                                  int* __restrict__ starts, int Tval) {
    int t = blockIdx.x * blockDim.x + threadIdx.x;
    if (t >= Tval) return;
    int b = seg[t];
    int a = (t == 0) ? -1 : seg[t - 1];
    for (int s = a + 1; s <= b; ++s) starts[s] = t;
}

// ---------------------------------------------------------------------------
// One wave per segment. Half-wave h (32 lanes) handles tokens t0+h, t0+h+2,...
// Each lane loads float4 (16 B) => one 512 B row per half-wave per instr,
// i.e. 2 tokens (1 KiB) per wave per instruction. Unroll 4 => 8 tokens/iter,
// 4 loads in flight per wave for latency hiding.
// ---------------------------------------------------------------------------
__global__ __launch_bounds__(256) void gather_mean_kernel(
    const int* __restrict__ tok, const float* __restrict__ emb,
    const int* __restrict__ starts, float* __restrict__ sent, int Bval) {
    int wave = threadIdx.x >> 6;
    int lane = threadIdx.x & 63;
    int s = blockIdx.x * 4 + wave;
    if (s >= Bval) return;

    int t0 = starts[s];
    int t1 = starts[s + 1];
    int cnt = t1 - t0;

    int half = lane >> 5;   // 0 or 1: which token of the pair
    int col  = lane & 31;   // float4 column within the 128-float row

    float4 acc = make_float4(0.f, 0.f, 0.f, 0.f);

    int i = t0 + half;      // this half-wave's token stream (stride 2)
    // unrolled: 4 tokens per half-wave per iter (indices i, i+2, i+4, i+6)
    for (; i + 6 < t1; i += 8) {
        int ta = tok[i];
        int tb = tok[i + 2];
        int tc = tok[i + 4];
        int td = tok[i + 6];
        float4 fa = ((const float4*)(emb + (size_t)ta * HDIM))[col];
        float4 fb = ((const float4*)(emb + (size_t)tb * HDIM))[col];
        float4 fc = ((const float4*)(emb + (size_t)tc * HDIM))[col];
        float4 fd = ((const float4*)(emb + (size_t)td * HDIM))[col];
        acc.x += fa.x + fb.x + fc.x + fd.x;
        acc.y += fa.y + fb.y + fc.y + fd.y;
        acc.z += fa.z + fb.z + fc.z + fd.z;
        acc.w += fa.w + fb.w + fc.w + fd.w;
    }
    for (; i < t1; i += 2) {
        int ta = tok[i];
        float4 fa = ((const float4*)(emb + (size_t)ta * HDIM))[col];
        acc.x += fa.x; acc.y += fa.y; acc.z += fa.z; acc.w += fa.w;
    }

    // combine the two half-wave partial sums (lane l += lane l+32)
    acc.x += __shfl_down(acc.x, 32);
    acc.y += __shfl_down(acc.y, 32);
    acc.z += __shfl_down(acc.z, 32);
    acc.w += __shfl_down(acc.w, 32);

    if (half == 0) {
        float inv = 1.0f / (float)(cnt > 0 ? cnt : 1);
        acc.x *= inv; acc.y *= inv; acc.z *= inv; acc.w *= inv;
        ((float4*)(sent + (size_t)s * HDIM))[col] = acc;
    }
}

// ---------------------------------------------------------------------------
// MLP head + BCE loss. W_hid (64 KB) staged once per block in LDS.
// Each wave register-blocks 4 segments: per k-step 1 ds_read_b64 (W pair) +
// 4 broadcast reads (sent) + 8 FMAs. Lane l owns output columns 2l, 2l+1.
// Output dot (W_out) via 64-lane shfl_xor reduce; one atomicAdd per block.
// ---------------------------------------------------------------------------
__global__ __launch_bounds__(256) void mlp_loss_kernel(
    const float* __restrict__ sent, const float* __restrict__ Wh,
    const float* __restrict__ bh, const float* __restrict__ Wo,
    const float* __restrict__ bo, const float* __restrict__ y,
    float* __restrict__ out, int Bval, int nblocks) {
    __shared__ float Wlds[HDIM * HDIM];       // 64 KB
    __shared__ float slds[4][4 * HDIM];       // 8 KB: 4 waves x 4 segments
    __shared__ float lred[4];

    for (int idx = threadIdx.x; idx < HDIM * HDIM / 4; idx += 256)
        ((float4*)Wlds)[idx] = ((const float4*)Wh)[idx];
    __syncthreads();

    int wave = threadIdx.x >> 6;
    int lane = threadIdx.x & 63;
    int j0 = lane * 2;

    float bh0 = bh[j0], bh1 = bh[j0 + 1];
    float wo0 = Wo[j0], wo1 = Wo[j0 + 1];
    float bov = bo[0];
    float lsum = 0.0f;

    const float2* W2 = (const float2*)Wlds;
    float* myld = &slds[wave][0];

    // base0 is block-uniform so __syncthreads (none inside) stays legal and
    // all waves execute the same trip count.
    for (int base0 = blockIdx.x * 16; base0 < Bval; base0 += nblocks * 16) {
        int base = base0 + wave * 4;
        int rem = Bval - base;
        int nseg = rem < 4 ? (rem < 0 ? 0 : rem) : 4;

        for (int r = 0; r < nseg; ++r) {
            float2 v = ((const float2*)(sent + (size_t)(base + r) * HDIM))[lane];
            ((float2*)(myld + r * HDIM))[lane] = v;
        }
        // same-wave LDS RAW: compiler inserts lgkmcnt waits.

        float a00 = bh0, a01 = bh1, a10 = bh0, a11 = bh1;
        float a20 = bh0, a21 = bh1, a30 = bh0, a31 = bh1;
        for (int i = 0; i < HDIM; ++i) {
            float2 w = W2[i * (HDIM / 2) + lane];
            float s0 = myld[0 * HDIM + i];
            float s1 = myld[1 * HDIM + i];
            float s2 = myld[2 * HDIM + i];
            float s3 = myld[3 * HDIM + i];
            a00 = fmaf(s0, w.x, a00); a01 = fmaf(s0, w.y, a01);
            a10 = fmaf(s1, w.x, a10); a11 = fmaf(s1, w.y, a11);
            a20 = fmaf(s2, w.x, a20); a21 = fmaf(s2, w.y, a21);
            a30 = fmaf(s3, w.x, a30); a31 = fmaf(s3, w.y, a31);
        }

        float pr0 = tanhf(a00) * wo0 + tanhf(a01) * wo1;
        float pr1 = tanhf(a10) * wo0 + tanhf(a11) * wo1;
        float pr2 = tanhf(a20) * wo0 + tanhf(a21) * wo1;
        float pr3 = tanhf(a30) * wo0 + tanhf(a31) * wo1;
        for (int m = 1; m < 64; m <<= 1) {
            pr0 += __shfl_xor(pr0, m);
            pr1 += __shfl_xor(pr1, m);
            pr2 += __shfl_xor(pr2, m);
            pr3 += __shfl_xor(pr3, m);
        }

        if (lane == 0) {
            float prs[4] = {pr0, pr1, pr2, pr3};
            for (int r = 0; r < nseg; ++r) {
                float z = prs[r] + bov;
                float p = 1.0f / (1.0f + expf(-z));
                float lp  = fmaxf(logf(p),     -100.0f);
                float l1p = fmaxf(log1pf(-p),  -100.0f);
                float yv = y[base + r];
                lsum -= yv * lp + (1.0f - yv) * l1p;
            }
        }
    }

    if (lane == 0) lred[wave] = lsum;
    __syncthreads();
    if (threadIdx.x == 0) {
        float tot = lred[0] + lred[1] + lred[2] + lred[3];
        atomicAdd(out, tot);
    }
}

// ---------------------------------------------------------------------------
extern "C" void kernel_launch(void* const* d_in, const int* in_sizes, int n_in,
                              void* d_out, int out_size, void* d_ws, size_t ws_size,
                              hipStream_t stream) {
    const int*   tok = (const int*)d_in[0];
    const int*   seg = (const int*)d_in[1];
    const float* y   = (const float*)d_in[2];
    const float* emb = (const float*)d_in[3];
    const float* Wh  = (const float*)d_in[4];
    const float* bh  = (const float*)d_in[5];
    const float* Wo  = (const float*)d_in[6];
    const float* bo  = (const float*)d_in[7];

    int T_ = in_sizes[0];
    int B_ = in_sizes[2];

    float* out = (float*)d_out;

    // ws layout: starts[B+1] ints (aligned to 256 B), then sent[B*H] floats.
    int* starts = (int*)d_ws;
    size_t starts_bytes = ((size_t)(B_ + 1) * sizeof(int) + 255) & ~(size_t)255;
    float* sent = (float*)((char*)d_ws + starts_bytes);

    init_kernel<<<(B_ + 1 + 255) / 256, 256, 0, stream>>>(starts, B_ + 1, T_, out);
    seg_bounds_kernel<<<(T_ + 255) / 256, 256, 0, stream>>>(seg, starts, T_);
    gather_mean_kernel<<<(B_ + 3) / 4, 256, 0, stream>>>(tok, emb, starts, sent, B_);
    int nblocks = (B_ + 15) / 16;
    if (nblocks > 256) nblocks = 256;
    mlp_loss_kernel<<<nblocks, 256, 0, stream>>>(sent, Wh, bh, Wo, bo, y, out, B_, nblocks);
}